// Round 11
// baseline (127.168 us; speedup 1.0000x reference)
//
#include <hip/hip_runtime.h>

// GAT edge softmax: alpha[i] = exp(e[i]) / (sum_{j: tgt[j]==tgt[i]} exp(e[j]) + 1e-16)
//
// Round-11: bin-then-scatter around the measured LDS-atomic law:
//   random-address wave64 LDS atomicAdd retires ~1 lane/cycle/CU (fits R4:
//   19.2M lane-ops=31us, R6: 38.4M=62us, R10: 6.4M=10us+overhead). So: pay
//   the ~10-15us atomic floor ONCE with everything else overlapped.
//
//   k1 gat_bin (1024 blk x 256 thr, LDS = 25 counters only): stream 6250-edge
//      slice; pk=(t&4095)<<16|f16(exp(e)); b=t>>12; slot=ds_add_rtn(lcnt[b]);
//      DIRECT global store buf[b][blk][slot] (4B, L2 merges granule lines).
//      Pad [m..CAP) with (j&4095)<<16 (spread indices, f16=+0.0 -> harmless).
//      CAP=352 (+6.6 sigma); overflow -> flag -> gated fallback.
//   k2 gat_scatter_bins (1600 blk = 25 buckets x 64 groups, 256 thr, 16KB
//      hist): block (b,g) reads ONE contiguous stream = 16 granules
//      ([b][g*16..g*16+16][CAP], 5632 u32 = 1408 uint4), FIXED 6-iteration
//      unrolled loop (5 unconditional + 1 guarded) -> loads pipeline ahead of
//      the 1-lane/cy ds_add drain. Pads add +0.0. Flush f16 partials (13.1MB).
//   k3/k4 reduce1/reduce2: 64 f16 copies -> 8 f32 subsums -> sums.
//   k5/k6 fb_zero/fb_scatter (gated on flag): device-atomic rebuild.
//   k7 normalize: alpha = exp(e) * rcp(sums[tgt]+1e-16).
//
// Dead ends (measured): device/workgroup-scope global atomics 327us (32B RMW
// memory-side); hot-address global counters ~500us; C-pass predicated replay
// wastes (C-1)/C atomic lane-ops; dynamic-trip-count list loops never
// pipeline (R8-R10 scatter stuck at 40us regardless of occupancy).

typedef unsigned long long ull;

#define NB 25
#define CHUNK_LG 12
#define CHUNK (1 << CHUNK_LG)            // 4096 nodes -> 16KB f32 hist
#define CCAP (NB * CHUNK)                // 102400 >= N=100000
#define BBLK 1024                        // bin blocks
#define BIN_THREADS 256
#define CAP 352                          // u32 per granule (mean 250, +6.6s), %4==0
#define SB 64                            // scatter groups per bucket
#define SRCPG (BBLK / SB)                // 16 granules per scatter block
#define SCB (NB * SB)                    // 1600 scatter blocks
#define SCAT_THREADS 256
#define STREAM_U4 (SRCPG * CAP / 4)      // 1408 uint4 per scatter block
#define NSUB 8

// d_ws layout (bytes): total ~55MB (ws >= 72MB proven in R7-R10)
#define SUMS_OFF 0u                      // CCAP f32 = 400KB
#define FLAG_OFF (448u * 1024u)
#define SUBS_OFF (512u * 1024u)          // NSUB*CCAP f32 = 3.28MB (ends <4MB)
#define BUF_OFF  (4u << 20)              // NB*BBLK*CAP u32 = 34.4MiB
#define PART_OFF (42u << 20)             // SCB*CHUNK f16 = 13.1MB (ends ~55MB)

__device__ __forceinline__ unsigned short f32_to_f16_bits(float x) {
    union { _Float16 h; unsigned short u; } cv;
    cv.h = (_Float16)x;
    return cv.u;
}
__device__ __forceinline__ float f16_bits_to_f32(unsigned short u) {
    union { unsigned short u; _Float16 h; } cv;
    cv.u = u;
    return (float)cv.h;
}
__device__ __forceinline__ unsigned pack_edge(int t, float x) {
    return ((unsigned)(t & (CHUNK - 1)) << 16) | (unsigned)f32_to_f16_bits(x);
}

// ---- k0: zero the overflow flag ----
__global__ void zero_flag(unsigned* __restrict__ flag) {
    if (threadIdx.x == 0) *flag = 0u;
}

// ---- k1: bin edges -> per-(bucket,block) global granules, no staging ----
__global__ __launch_bounds__(BIN_THREADS)
void gat_bin(const float* __restrict__ e, const int* __restrict__ tgt,
             unsigned* __restrict__ buf, unsigned* __restrict__ flag,
             int per, int E) {
    __shared__ unsigned lcnt[NB];
    __shared__ unsigned lovf;
    const int blk = blockIdx.x;
    const int tid = threadIdx.x;
    if (tid < NB) lcnt[tid] = 0;
    if (tid == 0) lovf = 0;
    __syncthreads();

    const long long start = (long long)blk * per;
    long long rem = (long long)E - start;
    if (rem < 0) rem = 0;
    int nv = per >> 2;
    if ((long long)nv > (rem >> 2)) nv = (int)(rem >> 2);
    const int tail_lo = nv * 4;
    int tail_hi = per;
    if ((long long)tail_hi > rem) tail_hi = (int)rem;

    const float4* e4 = reinterpret_cast<const float4*>(e + start);
    const int4*  t4 = reinterpret_cast<const int4*>(tgt + start);

#define BIN_ONE(T, X)                                                        \
    {   const int t_ = (T);                                                  \
        const unsigned b_ = (unsigned)t_ >> CHUNK_LG;                        \
        if (b_ < NB) {                                                       \
            const unsigned pk_ = pack_edge(t_, __expf(X));                   \
            const unsigned s_ = atomicAdd(&lcnt[b_], 1u);                    \
            if (s_ < CAP)                                                    \
                buf[((size_t)b_ * BBLK + blk) * CAP + s_] = pk_;             \
            else lovf = 1;                                                   \
        } else lovf = 1;                                                     \
    }
    for (int v = tid; v < nv; v += BIN_THREADS) {
        const float4 ev = e4[v];
        const int4 tv = t4[v];
        BIN_ONE(tv.x, ev.x)
        BIN_ONE(tv.y, ev.y)
        BIN_ONE(tv.z, ev.z)
        BIN_ONE(tv.w, ev.w)
    }
    for (int i = tail_lo + tid; i < tail_hi; i += BIN_THREADS) {
        BIN_ONE(tgt[start + i], e[start + i])
    }
#undef BIN_ONE
    __syncthreads();

    // zero-pad each granule [m..CAP) with spread indices + f16 0.0 payload
    // (scatter blindly adds +0.0 to hist[j&4095] -- harmless, no hot address)
#pragma unroll 5
    for (int b = 0; b < NB; ++b) {
        const unsigned m = min(lcnt[b], (unsigned)CAP);
        unsigned* dst = buf + ((size_t)b * BBLK + blk) * CAP;
        for (unsigned j = m + tid; j < CAP; j += BIN_THREADS)
            dst[j] = (j & (CHUNK - 1)) << 16;
    }
    if (tid == 0 && lovf) atomicOr(flag, 1u);
}

// ---- k2: per-bucket LDS hist scatter: fixed-trip uniform stream ----
__global__ __launch_bounds__(SCAT_THREADS)
void gat_scatter_bins(const unsigned* __restrict__ buf,
                      unsigned* __restrict__ partials) {
    __shared__ float hist[CHUNK];            // 16KB
    const int blk = blockIdx.x;
    const int b = blk / SB;
    const int g = blk - b * SB;
    const int tid = threadIdx.x;

    float4 z; z.x = z.y = z.z = z.w = 0.0f;
#pragma unroll
    for (int j = tid; j < CHUNK / 4; j += SCAT_THREADS)
        ((float4*)hist)[j] = z;
    __syncthreads();

    // one contiguous stream: 16 granules = 1408 uint4; k<5 guards fold away
    const uint4* s4 = reinterpret_cast<const uint4*>(
        buf + ((size_t)b * BBLK + (size_t)g * SRCPG) * CAP);
#pragma unroll
    for (int k = 0; k < 6; ++k) {
        const int v = tid + k * SCAT_THREADS;
        if (v < STREAM_U4) {
            const uint4 q = s4[v];
            atomicAdd(&hist[q.x >> 16], f16_bits_to_f32((unsigned short)q.x));
            atomicAdd(&hist[q.y >> 16], f16_bits_to_f32((unsigned short)q.y));
            atomicAdd(&hist[q.z >> 16], f16_bits_to_f32((unsigned short)q.z));
            atomicAdd(&hist[q.w >> 16], f16_bits_to_f32((unsigned short)q.w));
        }
    }
    __syncthreads();

    // flush 4096 f32 -> 2048 u32 (f16x2) as uint4 stores
    uint4* dst = (uint4*)(partials + (size_t)blk * (CHUNK / 2));
    const float4* h4 = (const float4*)hist;
#pragma unroll
    for (int j = tid; j < CHUNK / 8; j += SCAT_THREADS) {
        const float4 a = h4[2 * j];
        const float4 c = h4[2 * j + 1];
        uint4 o;
        o.x = (unsigned)f32_to_f16_bits(a.x) | ((unsigned)f32_to_f16_bits(a.y) << 16);
        o.y = (unsigned)f32_to_f16_bits(a.z) | ((unsigned)f32_to_f16_bits(a.w) << 16);
        o.z = (unsigned)f32_to_f16_bits(c.x) | ((unsigned)f32_to_f16_bits(c.y) << 16);
        o.w = (unsigned)f32_to_f16_bits(c.z) | ((unsigned)f32_to_f16_bits(c.w) << 16);
        dst[j] = o;
    }
}

// ---- k3: reduce 64 f16 copies -> 8 f32 subsums ----
__global__ void gat_reduce1(const unsigned short* __restrict__ partials,
                            float* __restrict__ subsums) {
    const int per_sub = CCAP >> 2;               // 25600 (mult of 64)
    const int t = blockIdx.x * blockDim.x + threadIdx.x;
    if (t >= per_sub * NSUB) return;
    const int sub = t / per_sub;
    const int r = t - sub * per_sub;
    const int nd = r << 2;
    const int b = nd >> CHUNK_LG;
    const int w = nd & (CHUNK - 1);
    const int blk0 = b * SB + sub * (SB / NSUB);
    const unsigned short* p = partials + ((size_t)blk0 * CHUNK) + w;
    float a0 = 0.f, a1 = 0.f, a2 = 0.f, a3 = 0.f;
#pragma unroll
    for (int s = 0; s < SB / NSUB; ++s) {
        const ushort4 v = *(const ushort4*)(p + (size_t)s * CHUNK);
        a0 += f16_bits_to_f32(v.x); a1 += f16_bits_to_f32(v.y);
        a2 += f16_bits_to_f32(v.z); a3 += f16_bits_to_f32(v.w);
    }
    float4 o; o.x = a0; o.y = a1; o.z = a2; o.w = a3;
    *(float4*)(subsums + (size_t)sub * CCAP + nd) = o;
}

// ---- k4: combine subsums -> sums ----
__global__ void gat_reduce2(const float* __restrict__ subsums,
                            const int* __restrict__ np,
                            float* __restrict__ sums) {
    const int n = *np;
    const int q = blockIdx.x * blockDim.x + threadIdx.x;
    const int nd = q * 4;
    if (nd >= CCAP) return;
    float4 acc; acc.x = acc.y = acc.z = acc.w = 0.f;
#pragma unroll
    for (int s = 0; s < NSUB; ++s) {
        const float4 v = *(const float4*)(subsums + (size_t)s * CCAP + nd);
        acc.x += v.x; acc.y += v.y; acc.z += v.z; acc.w += v.w;
    }
    if (nd + 4 <= n) {
        *(float4*)(sums + nd) = acc;
    } else {
        if (nd     < n) sums[nd]     = acc.x;
        if (nd + 1 < n) sums[nd + 1] = acc.y;
        if (nd + 2 < n) sums[nd + 2] = acc.z;
        if (nd + 3 < n) sums[nd + 3] = acc.w;
    }
}

// ---- k5/k6 (gated on overflow flag): safe device-atomic rebuild ----
__global__ void fb_zero(float* __restrict__ sums,
                        const unsigned* __restrict__ flag) {
    if (*flag == 0u) return;
    const int stride = gridDim.x * blockDim.x;
    for (int i = blockIdx.x * blockDim.x + threadIdx.x; i < CCAP; i += stride)
        sums[i] = 0.0f;
}

__global__ void fb_scatter(const float4* __restrict__ e4,
                           const int4* __restrict__ t4,
                           const float* __restrict__ e,
                           const int* __restrict__ tgt,
                           float* __restrict__ sums,
                           const unsigned* __restrict__ flag,
                           int n4, int E) {
    if (*flag == 0u) return;
    const int stride = gridDim.x * blockDim.x;
    const int tid = blockIdx.x * blockDim.x + threadIdx.x;
    for (int i = tid; i < n4; i += stride) {
        const float4 ev = e4[i];
        const int4 tv = t4[i];
        if ((unsigned)tv.x < (unsigned)CCAP) atomicAdd(&sums[tv.x], __expf(ev.x));
        if ((unsigned)tv.y < (unsigned)CCAP) atomicAdd(&sums[tv.y], __expf(ev.y));
        if ((unsigned)tv.z < (unsigned)CCAP) atomicAdd(&sums[tv.z], __expf(ev.z));
        if ((unsigned)tv.w < (unsigned)CCAP) atomicAdd(&sums[tv.w], __expf(ev.w));
    }
    const int tail_base = n4 * 4;
    for (int i = tail_base + tid; i < E; i += stride) {
        const int t = tgt[i];
        if ((unsigned)t < (unsigned)CCAP) atomicAdd(&sums[t], __expf(e[i]));
    }
}

// ---- tiny-ws fallback ----
__global__ void gat_zero_sums(float* __restrict__ sums,
                              const int* __restrict__ np) {
    const int n = *np;
    const int stride = gridDim.x * blockDim.x;
    for (int i = blockIdx.x * blockDim.x + threadIdx.x; i < n; i += stride)
        sums[i] = 0.0f;
}

__global__ void gat_exp_scatter(const float4* __restrict__ e4,
                                const int4* __restrict__ t4,
                                const float* __restrict__ e,
                                const int* __restrict__ tgt,
                                float* __restrict__ sums,
                                int n4, int E) {
    const int stride = gridDim.x * blockDim.x;
    const int tid = blockIdx.x * blockDim.x + threadIdx.x;
    for (int i = tid; i < n4; i += stride) {
        const float4 ev = e4[i];
        const int4 tv = t4[i];
        atomicAdd(&sums[tv.x], __expf(ev.x));
        atomicAdd(&sums[tv.y], __expf(ev.y));
        atomicAdd(&sums[tv.z], __expf(ev.z));
        atomicAdd(&sums[tv.w], __expf(ev.w));
    }
    const int tail_base = n4 * 4;
    if (tid < E - tail_base)
        atomicAdd(&sums[tgt[tail_base + tid]], __expf(e[tail_base + tid]));
}

// ---- k7: normalize ----
__global__ void gat_normalize(const float4* __restrict__ e4,
                              const int4* __restrict__ t4,
                              const float* __restrict__ e,
                              const int* __restrict__ tgt,
                              const float* __restrict__ sums,
                              float4* __restrict__ out4,
                              float* __restrict__ out,
                              int n4, int E) {
    const int stride = gridDim.x * blockDim.x;
    const int tid = blockIdx.x * blockDim.x + threadIdx.x;
    for (int i = tid; i < n4; i += stride) {
        const float4 ev = e4[i];
        const int4 tv = t4[i];
        float4 r;
        r.x = __expf(ev.x) * __builtin_amdgcn_rcpf(sums[tv.x] + 1e-16f);
        r.y = __expf(ev.y) * __builtin_amdgcn_rcpf(sums[tv.y] + 1e-16f);
        r.z = __expf(ev.z) * __builtin_amdgcn_rcpf(sums[tv.z] + 1e-16f);
        r.w = __expf(ev.w) * __builtin_amdgcn_rcpf(sums[tv.w] + 1e-16f);
        out4[i] = r;
    }
    const int tail_base = n4 * 4;
    if (tid < E - tail_base) {
        const int i = tail_base + tid;
        out[i] = __expf(e[i]) * __builtin_amdgcn_rcpf(sums[tgt[i]] + 1e-16f);
    }
}

extern "C" void kernel_launch(void* const* d_in, const int* in_sizes, int n_in,
                              void* d_out, int out_size, void* d_ws, size_t ws_size,
                              hipStream_t stream) {
    const float* e = (const float*)d_in[0];
    const int* edge_index = (const int*)d_in[1];   // [2, E] row-major
    const int* num_nodes_p = (const int*)d_in[2];  // device scalar

    const int E = in_sizes[0];
    const int* tgt = edge_index + E;               // row 1 = target nodes

    float* sums = (float*)((char*)d_ws + SUMS_OFF);
    float* alpha = (float*)d_out;
    const int n4e = E / 4;

    const int per = (((E + BBLK - 1) / BBLK) + 3) & ~3;   // 6252 @ E=6.4M

    const size_t need = (size_t)PART_OFF + (size_t)SCB * CHUNK * 2;  // ~55MB
    const bool use_bins = ws_size >= need;

    if (use_bins) {
        unsigned* flag = (unsigned*)((char*)d_ws + FLAG_OFF);
        float* subsums = (float*)((char*)d_ws + SUBS_OFF);
        unsigned* buf = (unsigned*)((char*)d_ws + BUF_OFF);
        unsigned* part_u32 = (unsigned*)((char*)d_ws + PART_OFF);
        unsigned short* part_u16 = (unsigned short*)part_u32;

        zero_flag<<<1, 64, 0, stream>>>(flag);

        gat_bin<<<BBLK, BIN_THREADS, 0, stream>>>(e, tgt, buf, flag, per, E);

        gat_scatter_bins<<<SCB, SCAT_THREADS, 0, stream>>>(buf, part_u32);

        gat_reduce1<<<(CCAP / 4) * NSUB / 256, 256, 0, stream>>>(part_u16, subsums);

        gat_reduce2<<<(CCAP / 4 + 255) / 256, 256, 0, stream>>>(
            subsums, num_nodes_p, sums);

        fb_zero<<<256, 256, 0, stream>>>(sums, flag);

        fb_scatter<<<1024, 256, 0, stream>>>(
            (const float4*)e, (const int4*)tgt, e, tgt, sums, flag, n4e, E);
    } else {
        gat_zero_sums<<<512, 256, 0, stream>>>(sums, num_nodes_p);
        int blocks = (n4e + 255) / 256;
        if (blocks > 2048) blocks = 2048;
        if (blocks < 1) blocks = 1;
        gat_exp_scatter<<<blocks, 256, 0, stream>>>(
            (const float4*)e, (const int4*)tgt, e, tgt, sums, n4e, E);
    }

    {
        int blocks = (n4e + 255) / 256;
        if (blocks < 1) blocks = 1;
        gat_normalize<<<blocks, 256, 0, stream>>>(
            (const float4*)e, (const int4*)tgt, e, tgt, sums,
            (float4*)alpha, alpha, n4e, E);
    }
}

// Round 12
// 126.246 us; speedup vs baseline: 1.0073x; 1.0073x over previous
//
#include <hip/hip_runtime.h>

// GAT edge softmax: alpha[i] = exp(e[i]) / (sum_{j: tgt[j]==tgt[i]} exp(e[j]) + 1e-16)
//
// Round-12: bin-then-scatter with FORCED memory parallelism.
//   R11 failed because the compiler serialized both hot kernels into
//   load->use->load->use (VGPR_Count=8!), exposing ~6 full memory latencies
//   per block with only 6.25 blocks/CU to cover them. Fix: batch-issue all
//   stream loads into PINNED register arrays (asm "+v") before any consumer.
//
//   k1 gat_bin (1024 blk x 256 thr, 35.2KB LDS stage -> 4 blk/CU): 7 pinned
//      (float4,int4) loads up front; per edge exp -> ds_add_rtn(lcnt[b]) ->
//      LDS stage[b*CAP+slot]; flush PAD-COMPLETE granules (uint4 coalesced,
//      pad = spread-index + f16 0.0) to buf[b][blk][CAP=352]. Overflow ->
//      flag -> gated device-atomic rebuild (correctness unconditional).
//   k2 gat_scatter_bins (1600 blk = 25 buckets x 64 groups, 256 thr, 16KB
//      f32 hist): 6 pinned uint4 loads (one contiguous 22.5KB stream = 16
//      granules) BEFORE the hist zero, then 24 blind ds_adds, flush f16
//      partials (13.1MB). No counts, no dynamic trips.
//   k3/k4 reduce1/reduce2: 64 f16 copies -> 8 f32 subsums -> sums.
//   k5/k6 fb_zero/fb_scatter (gated on flag).
//   k7 normalize: alpha = exp(e) * rcp(sums[tgt]+1e-16).
//
// Dead ends (measured): device/workgroup-scope global atomics 327us; hot-
// address global counters ~500us; C-pass predicated replay wastes (C-1)/C
// atomic ops; dynamic-trip list loops never pipeline; unpinned "unrolled"
// streams get register-starved into serial loads (R11: VGPR=8, 54us).

typedef unsigned long long ull;

#define NB 25
#define CHUNK_LG 12
#define CHUNK (1 << CHUNK_LG)            // 4096 nodes -> 16KB f32 hist
#define CCAP (NB * CHUNK)                // 102400 >= N=100000
#define BBLK 1024                        // bin blocks
#define BIN_THREADS 256
#define BKIT 7                           // pinned load batches in bin
#define CAP 352                          // u32 per granule (mean 250, +6.5s), %4==0
#define SB 64                            // scatter groups per bucket
#define SRCPG (BBLK / SB)                // 16 granules per scatter block
#define SCB (NB * SB)                    // 1600 scatter blocks
#define SCAT_THREADS 256
#define SKIT 6                           // pinned uint4 batches in scatter
#define STREAM_U4 (SRCPG * CAP / 4)      // 1408 uint4 per scatter block
#define NSUB 8

// d_ws layout (bytes): ~55MB total (ws >= 72MB proven R7-R11)
#define SUMS_OFF 0u                      // CCAP f32 = 400KB
#define FLAG_OFF (448u * 1024u)
#define SUBS_OFF (512u * 1024u)          // NSUB*CCAP f32 = 3.28MB (ends <4MB)
#define BUF_OFF  (4u << 20)              // NB*BBLK*CAP u32 = 34.4MiB
#define PART_OFF (42u << 20)             // SCB*CHUNK f16 = 13.1MB (ends ~55MB)

__device__ __forceinline__ unsigned short f32_to_f16_bits(float x) {
    union { _Float16 h; unsigned short u; } cv;
    cv.h = (_Float16)x;
    return cv.u;
}
__device__ __forceinline__ float f16_bits_to_f32(unsigned short u) {
    union { unsigned short u; _Float16 h; } cv;
    cv.u = u;
    return (float)cv.h;
}
__device__ __forceinline__ unsigned pack_edge(int t, float x) {
    return ((unsigned)(t & (CHUNK - 1)) << 16) | (unsigned)f32_to_f16_bits(x);
}

// ---- k0: zero the overflow flag ----
__global__ void zero_flag(unsigned* __restrict__ flag) {
    if (threadIdx.x == 0) *flag = 0u;
}

// ---- k1: bin edges -> pad-complete granules via LDS stage ----
__global__ __launch_bounds__(BIN_THREADS)
void gat_bin(const float* __restrict__ e, const int* __restrict__ tgt,
             unsigned* __restrict__ buf, unsigned* __restrict__ flag,
             int per, int E) {
    __shared__ unsigned stage[NB * CAP];     // 35.2KB
    __shared__ unsigned lcnt[NB];
    __shared__ unsigned lovf;
    const int blk = blockIdx.x;
    const int tid = threadIdx.x;
    if (tid < NB) lcnt[tid] = 0;
    if (tid == 0) lovf = 0;
    __syncthreads();

    const long long start = (long long)blk * per;
    long long rem = (long long)E - start;
    if (rem < 0) rem = 0;
    int nv = per >> 2;
    if ((long long)nv > (rem >> 2)) nv = (int)(rem >> 2);
    const int tail_lo = nv * 4;
    int tail_hi = per;
    if ((long long)tail_hi > rem) tail_hi = (int)rem;

    const float4* e4 = reinterpret_cast<const float4*>(e + start);
    const int4*  t4 = reinterpret_cast<const int4*>(tgt + start);

    // batch-issue ALL input loads, pinned so they can't be re-serialized
    float4 ev[BKIT];
    int4   tv[BKIT];
#pragma unroll
    for (int k = 0; k < BKIT; ++k) {
        const int v = tid + k * BIN_THREADS;
        if (v < nv) { ev[k] = e4[v]; tv[k] = t4[v]; }
        else {
            ev[k].x = ev[k].y = ev[k].z = ev[k].w = 0.0f;
            tv[k].x = tv[k].y = tv[k].z = tv[k].w = 0;
        }
    }
#pragma unroll
    for (int k = 0; k < BKIT; ++k) {
        asm volatile("" : "+v"(ev[k].x), "+v"(ev[k].y),
                          "+v"(ev[k].z), "+v"(ev[k].w),
                          "+v"(tv[k].x), "+v"(tv[k].y),
                          "+v"(tv[k].z), "+v"(tv[k].w));
    }

#define BIN_ONE(T, X)                                                        \
    {   const int t_ = (T);                                                  \
        const unsigned b_ = (unsigned)t_ >> CHUNK_LG;                        \
        if (b_ < NB) {                                                       \
            const unsigned pk_ = pack_edge(t_, __expf(X));                   \
            const unsigned s_ = atomicAdd(&lcnt[b_], 1u);                    \
            if (s_ < CAP) stage[b_ * CAP + s_] = pk_; else lovf = 1;         \
        } else lovf = 1;                                                     \
    }
#pragma unroll
    for (int k = 0; k < BKIT; ++k) {
        if (tid + k * BIN_THREADS < nv) {
            BIN_ONE(tv[k].x, ev[k].x)
            BIN_ONE(tv[k].y, ev[k].y)
            BIN_ONE(tv[k].z, ev[k].z)
            BIN_ONE(tv[k].w, ev[k].w)
        }
    }
    for (int i = tail_lo + tid; i < tail_hi; i += BIN_THREADS) {
        BIN_ONE(tgt[start + i], e[start + i])
    }
#undef BIN_ONE
    __syncthreads();

    // flush pad-complete granules: uint4 coalesced, pads are spread-index
    // words with f16 payload 0.0 (scatter blindly adds +0.0 -- harmless)
#pragma unroll 5
    for (int b = 0; b < NB; ++b) {
        const unsigned m = min(lcnt[b], (unsigned)CAP);
        uint4* dst = (uint4*)(buf + ((size_t)b * BBLK + blk) * CAP);
        const uint4* src = (const uint4*)(stage + b * CAP);
        for (int j4 = tid; j4 < CAP / 4; j4 += BIN_THREADS) {
            uint4 q = src[j4];
            const unsigned j = (unsigned)j4 * 4;
            if (j + 3 >= m) {
                if (j + 0 >= m) q.x = ((j + 0) & (CHUNK - 1)) << 16;
                if (j + 1 >= m) q.y = ((j + 1) & (CHUNK - 1)) << 16;
                if (j + 2 >= m) q.z = ((j + 2) & (CHUNK - 1)) << 16;
                if (j + 3 >= m) q.w = ((j + 3) & (CHUNK - 1)) << 16;
            }
            dst[j4] = q;
        }
    }
    if (tid == 0 && lovf) atomicOr(flag, 1u);
}

// ---- k2: per-bucket LDS hist scatter: pinned blind stream ----
__global__ __launch_bounds__(SCAT_THREADS)
void gat_scatter_bins(const unsigned* __restrict__ buf,
                      unsigned* __restrict__ partials) {
    __shared__ float hist[CHUNK];            // 16KB
    const int blk = blockIdx.x;
    const int b = blk / SB;
    const int g = blk - b * SB;
    const int tid = threadIdx.x;

    // issue ALL 6 stream loads first (pinned), overlapping the hist zero
    const uint4* s4 = reinterpret_cast<const uint4*>(
        buf + ((size_t)b * BBLK + (size_t)g * SRCPG) * CAP);
    uint4 q[SKIT];
#pragma unroll
    for (int k = 0; k < SKIT; ++k) {
        const int v = tid + k * SCAT_THREADS;
        if (v < STREAM_U4) q[k] = s4[v];
        else { q[k].x = q[k].y = q[k].z = q[k].w = 0u; }
    }
#pragma unroll
    for (int k = 0; k < SKIT; ++k) {
        asm volatile("" : "+v"(q[k].x), "+v"(q[k].y),
                          "+v"(q[k].z), "+v"(q[k].w));
    }

    float4 z; z.x = z.y = z.z = z.w = 0.0f;
#pragma unroll
    for (int j = tid; j < CHUNK / 4; j += SCAT_THREADS)
        ((float4*)hist)[j] = z;
    __syncthreads();

#pragma unroll
    for (int k = 0; k < SKIT; ++k) {
        if (tid + k * SCAT_THREADS < STREAM_U4) {
            atomicAdd(&hist[q[k].x >> 16], f16_bits_to_f32((unsigned short)q[k].x));
            atomicAdd(&hist[q[k].y >> 16], f16_bits_to_f32((unsigned short)q[k].y));
            atomicAdd(&hist[q[k].z >> 16], f16_bits_to_f32((unsigned short)q[k].z));
            atomicAdd(&hist[q[k].w >> 16], f16_bits_to_f32((unsigned short)q[k].w));
        }
    }
    __syncthreads();

    // flush 4096 f32 -> 2048 u32 (f16x2) as uint4 stores
    uint4* dst = (uint4*)(partials + (size_t)blk * (CHUNK / 2));
    const float4* h4 = (const float4*)hist;
#pragma unroll
    for (int j = tid; j < CHUNK / 8; j += SCAT_THREADS) {
        const float4 a = h4[2 * j];
        const float4 c = h4[2 * j + 1];
        uint4 o;
        o.x = (unsigned)f32_to_f16_bits(a.x) | ((unsigned)f32_to_f16_bits(a.y) << 16);
        o.y = (unsigned)f32_to_f16_bits(a.z) | ((unsigned)f32_to_f16_bits(a.w) << 16);
        o.z = (unsigned)f32_to_f16_bits(c.x) | ((unsigned)f32_to_f16_bits(c.y) << 16);
        o.w = (unsigned)f32_to_f16_bits(c.z) | ((unsigned)f32_to_f16_bits(c.w) << 16);
        dst[j] = o;
    }
}

// ---- k3: reduce 64 f16 copies -> 8 f32 subsums ----
__global__ void gat_reduce1(const unsigned short* __restrict__ partials,
                            float* __restrict__ subsums) {
    const int per_sub = CCAP >> 2;               // 25600 (mult of 64)
    const int t = blockIdx.x * blockDim.x + threadIdx.x;
    if (t >= per_sub * NSUB) return;
    const int sub = t / per_sub;
    const int r = t - sub * per_sub;
    const int nd = r << 2;
    const int b = nd >> CHUNK_LG;
    const int w = nd & (CHUNK - 1);
    const int blk0 = b * SB + sub * (SB / NSUB);
    const unsigned short* p = partials + ((size_t)blk0 * CHUNK) + w;
    float a0 = 0.f, a1 = 0.f, a2 = 0.f, a3 = 0.f;
#pragma unroll
    for (int s = 0; s < SB / NSUB; ++s) {
        const ushort4 v = *(const ushort4*)(p + (size_t)s * CHUNK);
        a0 += f16_bits_to_f32(v.x); a1 += f16_bits_to_f32(v.y);
        a2 += f16_bits_to_f32(v.z); a3 += f16_bits_to_f32(v.w);
    }
    float4 o; o.x = a0; o.y = a1; o.z = a2; o.w = a3;
    *(float4*)(subsums + (size_t)sub * CCAP + nd) = o;
}

// ---- k4: combine subsums -> sums ----
__global__ void gat_reduce2(const float* __restrict__ subsums,
                            const int* __restrict__ np,
                            float* __restrict__ sums) {
    const int n = *np;
    const int q = blockIdx.x * blockDim.x + threadIdx.x;
    const int nd = q * 4;
    if (nd >= CCAP) return;
    float4 acc; acc.x = acc.y = acc.z = acc.w = 0.f;
#pragma unroll
    for (int s = 0; s < NSUB; ++s) {
        const float4 v = *(const float4*)(subsums + (size_t)s * CCAP + nd);
        acc.x += v.x; acc.y += v.y; acc.z += v.z; acc.w += v.w;
    }
    if (nd + 4 <= n) {
        *(float4*)(sums + nd) = acc;
    } else {
        if (nd     < n) sums[nd]     = acc.x;
        if (nd + 1 < n) sums[nd + 1] = acc.y;
        if (nd + 2 < n) sums[nd + 2] = acc.z;
        if (nd + 3 < n) sums[nd + 3] = acc.w;
    }
}

// ---- k5/k6 (gated on overflow flag): safe device-atomic rebuild ----
__global__ void fb_zero(float* __restrict__ sums,
                        const unsigned* __restrict__ flag) {
    if (*flag == 0u) return;
    const int stride = gridDim.x * blockDim.x;
    for (int i = blockIdx.x * blockDim.x + threadIdx.x; i < CCAP; i += stride)
        sums[i] = 0.0f;
}

__global__ void fb_scatter(const float4* __restrict__ e4,
                           const int4* __restrict__ t4,
                           const float* __restrict__ e,
                           const int* __restrict__ tgt,
                           float* __restrict__ sums,
                           const unsigned* __restrict__ flag,
                           int n4, int E) {
    if (*flag == 0u) return;
    const int stride = gridDim.x * blockDim.x;
    const int tid = blockIdx.x * blockDim.x + threadIdx.x;
    for (int i = tid; i < n4; i += stride) {
        const float4 ev = e4[i];
        const int4 tv = t4[i];
        if ((unsigned)tv.x < (unsigned)CCAP) atomicAdd(&sums[tv.x], __expf(ev.x));
        if ((unsigned)tv.y < (unsigned)CCAP) atomicAdd(&sums[tv.y], __expf(ev.y));
        if ((unsigned)tv.z < (unsigned)CCAP) atomicAdd(&sums[tv.z], __expf(ev.z));
        if ((unsigned)tv.w < (unsigned)CCAP) atomicAdd(&sums[tv.w], __expf(ev.w));
    }
    const int tail_base = n4 * 4;
    for (int i = tail_base + tid; i < E; i += stride) {
        const int t = tgt[i];
        if ((unsigned)t < (unsigned)CCAP) atomicAdd(&sums[t], __expf(e[i]));
    }
}

// ---- tiny-ws fallback ----
__global__ void gat_zero_sums(float* __restrict__ sums,
                              const int* __restrict__ np) {
    const int n = *np;
    const int stride = gridDim.x * blockDim.x;
    for (int i = blockIdx.x * blockDim.x + threadIdx.x; i < n; i += stride)
        sums[i] = 0.0f;
}

__global__ void gat_exp_scatter(const float4* __restrict__ e4,
                                const int4* __restrict__ t4,
                                const float* __restrict__ e,
                                const int* __restrict__ tgt,
                                float* __restrict__ sums,
                                int n4, int E) {
    const int stride = gridDim.x * blockDim.x;
    const int tid = blockIdx.x * blockDim.x + threadIdx.x;
    for (int i = tid; i < n4; i += stride) {
        const float4 ev = e4[i];
        const int4 tv = t4[i];
        atomicAdd(&sums[tv.x], __expf(ev.x));
        atomicAdd(&sums[tv.y], __expf(ev.y));
        atomicAdd(&sums[tv.z], __expf(ev.z));
        atomicAdd(&sums[tv.w], __expf(ev.w));
    }
    const int tail_base = n4 * 4;
    if (tid < E - tail_base)
        atomicAdd(&sums[tgt[tail_base + tid]], __expf(e[tail_base + tid]));
}

// ---- k7: normalize ----
__global__ void gat_normalize(const float4* __restrict__ e4,
                              const int4* __restrict__ t4,
                              const float* __restrict__ e,
                              const int* __restrict__ tgt,
                              const float* __restrict__ sums,
                              float4* __restrict__ out4,
                              float* __restrict__ out,
                              int n4, int E) {
    const int stride = gridDim.x * blockDim.x;
    const int tid = blockIdx.x * blockDim.x + threadIdx.x;
    for (int i = tid; i < n4; i += stride) {
        const float4 ev = e4[i];
        const int4 tv = t4[i];
        float4 r;
        r.x = __expf(ev.x) * __builtin_amdgcn_rcpf(sums[tv.x] + 1e-16f);
        r.y = __expf(ev.y) * __builtin_amdgcn_rcpf(sums[tv.y] + 1e-16f);
        r.z = __expf(ev.z) * __builtin_amdgcn_rcpf(sums[tv.z] + 1e-16f);
        r.w = __expf(ev.w) * __builtin_amdgcn_rcpf(sums[tv.w] + 1e-16f);
        out4[i] = r;
    }
    const int tail_base = n4 * 4;
    if (tid < E - tail_base) {
        const int i = tail_base + tid;
        out[i] = __expf(e[i]) * __builtin_amdgcn_rcpf(sums[tgt[i]] + 1e-16f);
    }
}

extern "C" void kernel_launch(void* const* d_in, const int* in_sizes, int n_in,
                              void* d_out, int out_size, void* d_ws, size_t ws_size,
                              hipStream_t stream) {
    const float* e = (const float*)d_in[0];
    const int* edge_index = (const int*)d_in[1];   // [2, E] row-major
    const int* num_nodes_p = (const int*)d_in[2];  // device scalar

    const int E = in_sizes[0];
    const int* tgt = edge_index + E;               // row 1 = target nodes

    float* sums = (float*)((char*)d_ws + SUMS_OFF);
    float* alpha = (float*)d_out;
    const int n4e = E / 4;

    const int per = (((E + BBLK - 1) / BBLK) + 3) & ~3;   // 6252 @ E=6.4M

    const size_t need = (size_t)PART_OFF + (size_t)SCB * CHUNK * 2;  // ~55MB
    const bool use_bins =
        ws_size >= need && (per >> 2) <= BKIT * BIN_THREADS;  // pinned-cache cap

    if (use_bins) {
        unsigned* flag = (unsigned*)((char*)d_ws + FLAG_OFF);
        float* subsums = (float*)((char*)d_ws + SUBS_OFF);
        unsigned* buf = (unsigned*)((char*)d_ws + BUF_OFF);
        unsigned* part_u32 = (unsigned*)((char*)d_ws + PART_OFF);
        unsigned short* part_u16 = (unsigned short*)part_u32;

        zero_flag<<<1, 64, 0, stream>>>(flag);

        gat_bin<<<BBLK, BIN_THREADS, 0, stream>>>(e, tgt, buf, flag, per, E);

        gat_scatter_bins<<<SCB, SCAT_THREADS, 0, stream>>>(buf, part_u32);

        gat_reduce1<<<(CCAP / 4) * NSUB / 256, 256, 0, stream>>>(part_u16, subsums);

        gat_reduce2<<<(CCAP / 4 + 255) / 256, 256, 0, stream>>>(
            subsums, num_nodes_p, sums);

        fb_zero<<<256, 256, 0, stream>>>(sums, flag);

        fb_scatter<<<1024, 256, 0, stream>>>(
            (const float4*)e, (const int4*)tgt, e, tgt, sums, flag, n4e, E);
    } else {
        gat_zero_sums<<<512, 256, 0, stream>>>(sums, num_nodes_p);
        int blocks = (n4e + 255) / 256;
        if (blocks > 2048) blocks = 2048;
        if (blocks < 1) blocks = 1;
        gat_exp_scatter<<<blocks, 256, 0, stream>>>(
            (const float4*)e, (const int4*)tgt, e, tgt, sums, n4e, E);
    }

    {
        int blocks = (n4e + 255) / 256;
        if (blocks < 1) blocks = 1;
        gat_normalize<<<blocks, 256, 0, stream>>>(
            (const float4*)e, (const int4*)tgt, e, tgt, sums,
            (float4*)alpha, alpha, n4e, E);
    }
}